// Round 4
// baseline (1241.019 us; speedup 1.0000x reference)
//
#include <hip/hip_runtime.h>
#include <math.h>

#define NT 256
#define NTC 512
typedef _Float16 f16;
typedef _Float16 half8 __attribute__((ext_vector_type(8)));
typedef _Float16 half4 __attribute__((ext_vector_type(4)));
typedef float floatx4 __attribute__((ext_vector_type(4)));

// DPP row_shr sum (VALU-only reduce within 16-lane rows; full sum valid at l15==0 — HW-verified r3)
#define ROWSHR_ADD(v, N) \
  (v) += __int_as_float(__builtin_amdgcn_update_dpp(0, __float_as_int(v), 0x110 | (N), 0xF, 0xF, true))

// ---------------- workspace layout (bytes) ----------------
// Persistent: Wd1p, Wd2p, WoT, d8, hbuf, d1buf.
// Wpk (capsule weights) lives at the START of the d1 region: written by prep, read only by
// k_caps, dead before k_dec#1 writes d1buf (stream-ordered). fp32 prep scratch lives at the
// start of the hbuf region: dead before k_caps writes hbuf.
#define WD1_OFF  0              // 896*800*2 = 1433600
#define WD2_OFF  1433600
#define WOT_OFF  2867200        // 784*16*4 = 50176
#define D8_OFF   2917376        // 196*4 = 784 (pad to 2918400)
#define HBUF_OFF 2918400        // 32768*800*2 = 52428800 -> end 55347200
#define D1_OFF   55347200       // 52428800 -> end 107776000
#define WPKH_OFF 55347200       // 9*208*224*2 = 838656
#define WPKL_OFF 56185856       // 838656 -> end 57024512 (inside d1 region)
#define SSE      38464          // scratch slot stride in floats (>=196*196)
// scratch slots (floats, at hbuf base): 0:G  1..8:K_1..K_8  9..15:T_1..7  16..22:H_1..7  23:gtab(8*196)

__device__ inline void glds16(const void* g, void* l) {
  __builtin_amdgcn_global_load_lds((const __attribute__((address_space(1))) void*)g,
                                   (__attribute__((address_space(3))) void*)l, 16, 0, 0);
}

// ---------------- prep: decoder weights (unchanged) ----------------
__global__ void k_prep_wd(const float* __restrict__ Wd, f16* __restrict__ W16) {
  int idx = blockIdx.x * NT + threadIdx.x;
  if (idx >= 896 * 800) return;
  int n = idx / 800, k = idx - n * 800;
  W16[idx] = (f16)((n < 784 && k < 784) ? Wd[n * 784 + k] : 0.f);
}

__global__ void k_prep_wo(const float* __restrict__ Wo, float* __restrict__ WoT) {
  int idx = blockIdx.x * NT + threadIdx.x;
  if (idx >= 784 * 16) return;
  int f = idx >> 4, n = idx & 15;
  WoT[idx] = (n < 10) ? Wo[n * 784 + f] : 0.f;
}

// ---------------- prep: small fp32 196x196 GEMM (batched via blockIdx.y) ----------------
__global__ void k_mm(const float* __restrict__ A, const float* __restrict__ B,
                     float* __restrict__ C, int ta, int tb, int sA, int sB, int sC) {
  A += (size_t)blockIdx.y * sA;
  B += (size_t)blockIdx.y * sB;
  C += (size_t)blockIdx.y * sC;
  int idx = blockIdx.x * NT + threadIdx.x;
  if (idx >= 196 * 196) return;
  int p = idx / 196, r = idx - p * 196;
  float s = 0.f;
  for (int c = 0; c < 196; ++c) {
    float a = ta ? A[c * 196 + p] : A[p * 196 + c];
    float b = tb ? B[r * 196 + c] : B[c * 196 + r];
    s += a * b;
  }
  C[p * 196 + r] = s;
}

__global__ void k_tr(const float* __restrict__ A, float* __restrict__ C) {
  int idx = blockIdx.x * NT + threadIdx.x;
  if (idx >= 196 * 196) return;
  int p = idx / 196, r = idx - p * 196;
  C[p * 196 + r] = A[r * 196 + p];
}

// ---------------- prep: vectors (d-chain, z, g_i, ghat_i, d8) ----------------
__global__ void k_prep_vec(const float* __restrict__ W2, const float* __restrict__ b1,
                           const float* __restrict__ W3, const float* __restrict__ b3,
                           const float* __restrict__ G, const float* __restrict__ Kbase,
                           float* __restrict__ gtab, float* __restrict__ d8out) {
  __shared__ float d[196], z[196], u[196], v[196];
  const int t = threadIdx.x;
  if (t < 196) {
    float s = 0.f;
    for (int f = 0; f < 196; ++f) s += b1[f] * W2[f * 196 + t];
    z[t] = s;
    d[t] = 0.f;
  }
  __syncthreads();
  for (int i = 0; i < 8; ++i) {
    if (t < 196) {                       // g_i[n] = sum_k G[k][n] d[k] + z[n]
      float s = z[t];
      for (int k = 0; k < 196; ++k) s += G[k * 196 + t] * d[k];
      u[t] = s;
    }
    __syncthreads();
    if (i == 0) {
      if (t < 196) gtab[t] = u[t];       // K_0 = I
    } else {
      const float* Ki = Kbase + (size_t)(i - 1) * SSE;
      if (t < 196) {                     // ghat_i[k] = sum_n K_i[k][n] g_i[n]
        float s = 0.f;
        for (int n = 0; n < 196; ++n) s += Ki[t * 196 + n] * u[n];
        v[t] = s;
      }
      __syncthreads();
      if (t < 196) gtab[i * 196 + t] = v[t];
    }
    __syncthreads();
    if (t < 196) {                       // d = W3 d + b3
      float s = b3[t];
      for (int c = 0; c < 196; ++c) s += W3[t * 196 + c] * d[c];
      v[t] = s;
    }
    __syncthreads();
    if (t < 196) d[t] = v[t];
    __syncthreads();
  }
  if (t < 196) d8out[t] = d[t];
}

// ---------------- prep: pack Wpk[9 slots][208 n][224 k] f16 hi/lo ----------------
// slot s<8: B[k][n] = H_s[k][n] (H_0 = G); col n==196 carries ghat_s[k]. slot 8: K_8[k][n].
__global__ void k_prep_pack(const float* __restrict__ scr,
                            f16* __restrict__ Wph, f16* __restrict__ Wpl) {
  int idx = blockIdx.x * NT + threadIdx.x;
  if (idx >= 9 * 208 * 224) return;
  int s = idx / (208 * 224), rem = idx - s * (208 * 224);
  int n = rem / 224, k = rem - n * 224;
  float v = 0.f;
  if (k < 196) {
    if (n < 196) {
      const float* M = (s == 0) ? scr
                     : (s < 8 ? (scr + (size_t)(16 + s - 1) * SSE)
                              : (scr + (size_t)8 * SSE));
      v = M[k * 196 + n];
    } else if (n == 196 && s < 8) {
      v = scr[(size_t)23 * SSE + s * 196 + k];
    }
  }
  f16 hi = (f16)v;
  Wph[idx] = hi;
  Wpl[idx] = (f16)(v - (float)hi);
}

// ---------------- capsule kernel: 8 independent Y_i GEMMs + 4x4 C-chain + V_8 ----------------
__global__ __launch_bounds__(NTC, 4)
void k_caps(const float* __restrict__ x,
            const f16* __restrict__ Wph, const f16* __restrict__ Wpl,
            const float* __restrict__ d8g,
            f16* __restrict__ hbuf) {
  __shared__ __align__(16) char smem[70656];
  f16*   vAhi = (f16*)smem;                 // [64][232]
  f16*   vAlo = (f16*)(smem + 29696);       // [64][232]
  float* Sful = (float*)(smem + 59392);     // [8 i][16 elem][4 t][4 s] = 2048 f
  float* Rl   = (float*)(smem + 67584);     // [8 i][64 row] = 512 f
  float* Cm   = (float*)(smem + 69632);     // [16 elem][4 t][4 s] = 256 f

  const int tid  = threadIdx.x;
  const int w    = tid >> 6;                // 0..7
  const int lane = tid & 63;
  const int l15  = lane & 15;
  const int quad = lane >> 4;
  const int e0   = blockIdx.x * 16;
  const bool haveJ1 = (w + 8) < 13;         // w<5

  // ---- stage v0 = x (hi/lo f16), float4 path ----
  for (int idx = tid; idx < 16 * 196; idx += NTC) {
    int elem = idx / 196, g = idx - elem * 196;
    int t = g / 49, f = (g - t * 49) * 4;
    floatx4 v4 = *(const floatx4*)&x[(size_t)(e0 + elem) * 784 + g * 4];
    half4 h4, l4;
    #pragma unroll
    for (int q = 0; q < 4; ++q) {
      f16 h = (f16)v4[q];
      h4[q] = h;
      l4[q] = (f16)(v4[q] - (float)h);
    }
    int vo = (elem * 4 + t) * 232 + f;
    *(half4*)&vAhi[vo] = h4;
    *(half4*)&vAlo[vo] = l4;
  }
  for (int p = tid; p < 64 * 36; p += NTC) {
    int row = p / 36, c = 196 + (p - (p / 36) * 36);
    vAhi[row * 232 + c] = (f16)0;
    vAlo[row * 232 + c] = (f16)0;
  }
  for (int p = tid; p < 2048; p += NTC) Sful[p] = 0.f;
  __syncthreads();

  // ---- vv preload: v values at this wave's score columns (fp32, combined) ----
  float vv0[4][4], vv1[4][4];
  {
    int c0 = w * 16 + l15;            // < 128, always a valid v column
    int c1 = 128 + w * 16 + l15;      // only when haveJ1; cols>=196 read zero-pad
    #pragma unroll
    for (int mt = 0; mt < 4; ++mt)
      #pragma unroll
      for (int s = 0; s < 4; ++s) {
        int ro = ((mt * 4 + quad) * 4 + s) * 232;
        vv0[mt][s] = (float)vAhi[ro + c0] + (float)vAlo[ro + c0];
        vv1[mt][s] = haveJ1 ? ((float)vAhi[ro + c1] + (float)vAlo[ro + c1]) : 0.f;
      }
  }

  // ---- phase 1: 8 independent Y_i GEMMs, no barriers ----
  #pragma unroll 1
  for (int i = 0; i < 8; ++i) {
    floatx4 acc0[4], acc1[4];
    #pragma unroll
    for (int mt = 0; mt < 4; ++mt) {
      acc0[mt] = (floatx4){0.f, 0.f, 0.f, 0.f};
      acc1[mt] = (floatx4){0.f, 0.f, 0.f, 0.f};
    }
    const int wb0 = ((i * 208 + w * 16 + l15) * 224) + quad * 8;
    const int wb1 = ((i * 208 + (w + 8) * 16 + l15) * 224) + quad * 8;
    #pragma unroll
    for (int ks = 0; ks < 7; ++ks) {
      half8 ah[4], al[4];
      #pragma unroll
      for (int mt = 0; mt < 4; ++mt) {
        int ao = (mt * 16 + l15) * 232 + ks * 32 + quad * 8;
        ah[mt] = *(const half8*)&vAhi[ao];
        al[mt] = *(const half8*)&vAlo[ao];
      }
      {
        half8 bh = *(const half8*)&Wph[wb0 + ks * 32];
        half8 bl = *(const half8*)&Wpl[wb0 + ks * 32];
        #pragma unroll
        for (int mt = 0; mt < 4; ++mt) {
          acc0[mt] = __builtin_amdgcn_mfma_f32_16x16x32_f16(ah[mt], bh, acc0[mt], 0, 0, 0);
          acc0[mt] = __builtin_amdgcn_mfma_f32_16x16x32_f16(ah[mt], bl, acc0[mt], 0, 0, 0);
          acc0[mt] = __builtin_amdgcn_mfma_f32_16x16x32_f16(al[mt], bh, acc0[mt], 0, 0, 0);
        }
      }
      if (haveJ1) {
        half8 bh = *(const half8*)&Wph[wb1 + ks * 32];
        half8 bl = *(const half8*)&Wpl[wb1 + ks * 32];
        #pragma unroll
        for (int mt = 0; mt < 4; ++mt) {
          acc1[mt] = __builtin_amdgcn_mfma_f32_16x16x32_f16(ah[mt], bh, acc1[mt], 0, 0, 0);
          acc1[mt] = __builtin_amdgcn_mfma_f32_16x16x32_f16(ah[mt], bl, acc1[mt], 0, 0, 0);
          acc1[mt] = __builtin_amdgcn_mfma_f32_16x16x32_f16(al[mt], bh, acc1[mt], 0, 0, 0);
        }
      }
    }
    // scores: M_i[t][s] partials = Y_i[t][col] * v[s][col], DPP reduce, atomic accumulate
    #pragma unroll
    for (int mt = 0; mt < 4; ++mt) {
      float part[16];
      #pragma unroll
      for (int t = 0; t < 4; ++t)
        #pragma unroll
        for (int s = 0; s < 4; ++s)
          part[t * 4 + s] = acc0[mt][t] * vv0[mt][s] + acc1[mt][t] * vv1[mt][s];
      #pragma unroll
      for (int p = 0; p < 16; ++p) {
        ROWSHR_ADD(part[p], 8);
        ROWSHR_ADD(part[p], 4);
        ROWSHR_ADD(part[p], 2);
        ROWSHR_ADD(part[p], 1);
      }
      if (l15 == 0) {
        int elem = mt * 4 + quad;
        #pragma unroll
        for (int t = 0; t < 4; ++t)
          #pragma unroll
          for (int s = 0; s < 4; ++s)
            atomicAdd(&Sful[((i * 16 + elem) * 4 + t) * 4 + s], part[t * 4 + s]);
      }
    }
    // r_i column (ghat col 196 lives in nt=12 -> w==4, j==1, l15==4)
    if (w == 4 && l15 == 4) {
      #pragma unroll
      for (int mt = 0; mt < 4; ++mt)
        *(floatx4*)&Rl[i * 64 + mt * 16 + quad * 4] = acc1[mt];
    }
  }
  __syncthreads();

  // ---- phase 2: per-element 4x4 C-chain (C_{i+1} = P_i C_i) ----
  if (tid < 16) {
    const int e = tid;
    float C[4][4] = {{1,0,0,0},{0,1,0,0},{0,0,1,0},{0,0,0,1}};
    #pragma unroll 1
    for (int i = 0; i < 8; ++i) {
      float M[4][4];
      #pragma unroll
      for (int a = 0; a < 4; ++a) {
        floatx4 mm = *(const floatx4*)&Sful[((i * 16 + e) * 4 + a) * 4];
        #pragma unroll
        for (int b = 0; b < 4; ++b) M[a][b] = mm[b];
      }
      floatx4 rv = *(const floatx4*)&Rl[i * 64 + e * 4];
      float T1[4][4], Cr[4];
      #pragma unroll
      for (int t = 0; t < 4; ++t)
        #pragma unroll
        for (int b = 0; b < 4; ++b)
          T1[t][b] = C[t][0]*M[0][b] + C[t][1]*M[1][b] + C[t][2]*M[2][b] + C[t][3]*M[3][b];
      #pragma unroll
      for (int s = 0; s < 4; ++s)
        Cr[s] = C[s][0]*rv[0] + C[s][1]*rv[1] + C[s][2]*rv[2] + C[s][3]*rv[3];
      float P[4][4];
      #pragma unroll
      for (int t = 0; t < 4; ++t) {
        float S[4];
        #pragma unroll
        for (int s = 0; s < 4; ++s)
          S[s] = T1[t][0]*C[s][0] + T1[t][1]*C[s][1] + T1[t][2]*C[s][2] + T1[t][3]*C[s][3] + Cr[s];
        float m = fmaxf(fmaxf(S[0], S[1]), fmaxf(S[2], S[3]));
        float e0_ = __expf(S[0] - m), e1 = __expf(S[1] - m);
        float e2 = __expf(S[2] - m), e3 = __expf(S[3] - m);
        float inv = 1.f / (e0_ + e1 + e2 + e3);
        P[t][0] = e0_ * inv; P[t][1] = e1 * inv; P[t][2] = e2 * inv; P[t][3] = e3 * inv;
      }
      float Cn[4][4];
      #pragma unroll
      for (int t = 0; t < 4; ++t)
        #pragma unroll
        for (int s = 0; s < 4; ++s)
          Cn[t][s] = P[t][0]*C[0][s] + P[t][1]*C[1][s] + P[t][2]*C[2][s] + P[t][3]*C[3][s];
      #pragma unroll
      for (int t = 0; t < 4; ++t)
        #pragma unroll
        for (int s = 0; s < 4; ++s) C[t][s] = Cn[t][s];
    }
    #pragma unroll
    for (int t = 0; t < 4; ++t)
      *(floatx4*)&Cm[e * 16 + t * 4] = (floatx4){C[t][0], C[t][1], C[t][2], C[t][3]};
  }
  __syncthreads();

  // ---- phase 3: V_8 = v0 K_8 GEMM, h = C_8 V_8 + d8, direct global store ----
  {
    floatx4 acu0[4], acu1[4];
    #pragma unroll
    for (int mt = 0; mt < 4; ++mt) {
      acu0[mt] = (floatx4){0.f, 0.f, 0.f, 0.f};
      acu1[mt] = (floatx4){0.f, 0.f, 0.f, 0.f};
    }
    const int wb0 = ((8 * 208 + w * 16 + l15) * 224) + quad * 8;
    const int wb1 = ((8 * 208 + (w + 8) * 16 + l15) * 224) + quad * 8;
    #pragma unroll
    for (int ks = 0; ks < 7; ++ks) {
      half8 ah[4], al[4];
      #pragma unroll
      for (int mt = 0; mt < 4; ++mt) {
        int ao = (mt * 16 + l15) * 232 + ks * 32 + quad * 8;
        ah[mt] = *(const half8*)&vAhi[ao];
        al[mt] = *(const half8*)&vAlo[ao];
      }
      {
        half8 bh = *(const half8*)&Wph[wb0 + ks * 32];
        half8 bl = *(const half8*)&Wpl[wb0 + ks * 32];
        #pragma unroll
        for (int mt = 0; mt < 4; ++mt) {
          acu0[mt] = __builtin_amdgcn_mfma_f32_16x16x32_f16(ah[mt], bh, acu0[mt], 0, 0, 0);
          acu0[mt] = __builtin_amdgcn_mfma_f32_16x16x32_f16(ah[mt], bl, acu0[mt], 0, 0, 0);
          acu0[mt] = __builtin_amdgcn_mfma_f32_16x16x32_f16(al[mt], bh, acu0[mt], 0, 0, 0);
        }
      }
      if (haveJ1) {
        half8 bh = *(const half8*)&Wph[wb1 + ks * 32];
        half8 bl = *(const half8*)&Wpl[wb1 + ks * 32];
        #pragma unroll
        for (int mt = 0; mt < 4; ++mt) {
          acu1[mt] = __builtin_amdgcn_mfma_f32_16x16x32_f16(ah[mt], bh, acu1[mt], 0, 0, 0);
          acu1[mt] = __builtin_amdgcn_mfma_f32_16x16x32_f16(ah[mt], bl, acu1[mt], 0, 0, 0);
          acu1[mt] = __builtin_amdgcn_mfma_f32_16x16x32_f16(al[mt], bh, acu1[mt], 0, 0, 0);
        }
      }
    }
    const int f0 = w * 16 + l15;            // < 128
    const int f1 = 128 + w * 16 + l15;
    const bool doF1 = haveJ1 && (f1 < 196);
    float d80 = d8g[f0];
    float d81 = doF1 ? d8g[f1] : 0.f;
    #pragma unroll
    for (int mt = 0; mt < 4; ++mt) {
      int elem = mt * 4 + quad;
      floatx4 c0 = *(const floatx4*)&Cm[elem * 16 + 0];
      floatx4 c1 = *(const floatx4*)&Cm[elem * 16 + 4];
      floatx4 c2 = *(const floatx4*)&Cm[elem * 16 + 8];
      floatx4 c3 = *(const floatx4*)&Cm[elem * 16 + 12];
      {
        floatx4 u = acu0[mt];
        float h0 = c0[0]*u[0] + c0[1]*u[1] + c0[2]*u[2] + c0[3]*u[3] + d80;
        float h1 = c1[0]*u[0] + c1[1]*u[1] + c1[2]*u[2] + c1[3]*u[3] + d80;
        float h2 = c2[0]*u[0] + c2[1]*u[1] + c2[2]*u[2] + c2[3]*u[3] + d80;
        float h3 = c3[0]*u[0] + c3[1]*u[1] + c3[2]*u[2] + c3[3]*u[3] + d80;
        size_t base = (size_t)(e0 + elem) * 800;
        hbuf[base + 0 * 196 + f0] = (f16)h0;
        hbuf[base + 1 * 196 + f0] = (f16)h1;
        hbuf[base + 2 * 196 + f0] = (f16)h2;
        hbuf[base + 3 * 196 + f0] = (f16)h3;
      }
      if (doF1) {
        floatx4 u = acu1[mt];
        float h0 = c0[0]*u[0] + c0[1]*u[1] + c0[2]*u[2] + c0[3]*u[3] + d81;
        float h1 = c1[0]*u[0] + c1[1]*u[1] + c1[2]*u[2] + c1[3]*u[3] + d81;
        float h2 = c2[0]*u[0] + c2[1]*u[1] + c2[2]*u[2] + c2[3]*u[3] + d81;
        float h3 = c3[0]*u[0] + c3[1]*u[1] + c3[2]*u[2] + c3[3]*u[3] + d81;
        size_t base = (size_t)(e0 + elem) * 800;
        hbuf[base + 0 * 196 + f1] = (f16)h0;
        hbuf[base + 1 * 196 + f1] = (f16)h1;
        hbuf[base + 2 * 196 + f1] = (f16)h2;
        hbuf[base + 3 * 196 + f1] = (f16)h3;
      }
    }
  }
  // zero-fill padding cols 784..799
  for (int idx = tid; idx < 256; idx += NTC)
    hbuf[(size_t)(e0 + (idx >> 4)) * 800 + 784 + (idx & 15)] = (f16)0;
}

// ---------------- decoder layer GEMM (unchanged) ----------------
__global__ __launch_bounds__(NT, 2)
void k_dec(const f16* __restrict__ A, const f16* __restrict__ Bw,
           const float* __restrict__ bias, f16* __restrict__ C, int do_relu) {
  __shared__ __align__(16) f16 As[128 * 32];
  __shared__ __align__(16) f16 Bs[128 * 32];
  const int tid = threadIdx.x, w = tid >> 6, lane = tid & 63;
  const int l15 = lane & 15, quad = lane >> 4;
  const int m0 = blockIdx.x * 128, n0 = blockIdx.y * 128;
  const int wm = w & 1, wn = w >> 1;
  const int srow = lane >> 2, soff = (lane & 3) * 8;

  floatx4 acc[4][4];
  #pragma unroll
  for (int nt = 0; nt < 4; ++nt) {
    int col = n0 + wn * 64 + nt * 16 + l15;
    float bb = (col < 784) ? bias[col] : 0.f;
    #pragma unroll
    for (int mt = 0; mt < 4; ++mt) acc[mt][nt] = (floatx4){bb, bb, bb, bb};
  }

  for (int kk = 0; kk < 25; ++kk) {
    __syncthreads();
    #pragma unroll
    for (int i = 0; i < 2; ++i) {
      int r = w * 32 + i * 16;
      glds16(&A[(size_t)(m0 + r + srow) * 800 + kk * 32 + soff], &As[r * 32]);
      glds16(&Bw[(size_t)(n0 + r + srow) * 800 + kk * 32 + soff], &Bs[r * 32]);
    }
    __syncthreads();
    half8 af[4], bf[4];
    #pragma unroll
    for (int mt = 0; mt < 4; ++mt)
      af[mt] = *(const half8*)&As[(wm * 64 + mt * 16 + l15) * 32 + quad * 8];
    #pragma unroll
    for (int nt = 0; nt < 4; ++nt)
      bf[nt] = *(const half8*)&Bs[(wn * 64 + nt * 16 + l15) * 32 + quad * 8];
    #pragma unroll
    for (int mt = 0; mt < 4; ++mt)
      #pragma unroll
      for (int nt = 0; nt < 4; ++nt)
        acc[mt][nt] = __builtin_amdgcn_mfma_f32_16x16x32_f16(af[mt], bf[nt], acc[mt][nt], 0, 0, 0);
  }

  #pragma unroll
  for (int nt = 0; nt < 4; ++nt) {
    int gcol = n0 + wn * 64 + nt * 16 + l15;
    if (gcol < 800) {
      #pragma unroll
      for (int mt = 0; mt < 4; ++mt) {
        #pragma unroll
        for (int r = 0; r < 4; ++r) {
          int grow = m0 + wm * 64 + mt * 16 + quad * 4 + r;
          float v = acc[mt][nt][r];
          if (do_relu) v = fmaxf(v, 0.f);
          C[(size_t)grow * 800 + gcol] = (f16)v;
        }
      }
    }
  }
}

// ---------------- logits + softmax (unchanged) ----------------
__global__ __launch_bounds__(NT, 4)
void k_logits(const f16* __restrict__ d2, const float* __restrict__ WoT,
              const float* __restrict__ bo, float* __restrict__ out) {
  __shared__ __align__(16) f16 ds[16 * 800];
  __shared__ float lg[160];
  const int tid = threadIdx.x;
  const size_t e0 = (size_t)blockIdx.x * 16;
  for (int i = tid; i < 16 * 98; i += NT) {
    int e = i / 98, c = (i - e * 98) * 8;
    *(half8*)&ds[e * 800 + c] = *(const half8*)&d2[(e0 + e) * 800 + c];
  }
  __syncthreads();
  {
    int e = tid >> 4, n = tid & 15;
    const f16* dp = &ds[e * 800];
    float s = 0.f;
    #pragma unroll 4
    for (int f = 0; f < 784; ++f) s += (float)dp[f] * WoT[f * 16 + n];
    if (n < 10) lg[e * 10 + n] = s + bo[n];
  }
  __syncthreads();
  if (tid < 16) {
    float l[10], m = -1e30f;
    #pragma unroll
    for (int n = 0; n < 10; ++n) { l[n] = lg[tid * 10 + n]; m = fmaxf(m, l[n]); }
    float sum = 0.f;
    #pragma unroll
    for (int n = 0; n < 10; ++n) { l[n] = __expf(l[n] - m); sum += l[n]; }
    float inv = 1.f / sum;
    #pragma unroll
    for (int n = 0; n < 10; ++n) out[(e0 + tid) * 10 + n] = l[n] * inv;
  }
}

extern "C" void kernel_launch(void* const* d_in, const int* in_sizes, int n_in,
                              void* d_out, int out_size, void* d_ws, size_t ws_size,
                              hipStream_t stream) {
  const float* x   = (const float*)d_in[0];
  const float* W1  = (const float*)d_in[1];
  const float* b1  = (const float*)d_in[2];
  const float* W2  = (const float*)d_in[3];
  // b2 (d_in[4]) cancels in the softmax (row-constant) — unused.
  const float* W3  = (const float*)d_in[5];
  const float* b3  = (const float*)d_in[6];
  const float* Wd1 = (const float*)d_in[7];
  const float* bd1 = (const float*)d_in[8];
  const float* Wd2 = (const float*)d_in[9];
  const float* bd2 = (const float*)d_in[10];
  const float* Wo  = (const float*)d_in[11];
  const float* bo  = (const float*)d_in[12];
  float* out = (float*)d_out;

  char* ws = (char*)d_ws;
  f16*   Wd1p  = (f16*)(ws + WD1_OFF);
  f16*   Wd2p  = (f16*)(ws + WD2_OFF);
  float* WoTws = (float*)(ws + WOT_OFF);
  float* d8ws  = (float*)(ws + D8_OFF);
  f16*   hbuf  = (f16*)(ws + HBUF_OFF);
  f16*   d1buf = (f16*)(ws + D1_OFF);
  f16*   Wph   = (f16*)(ws + WPKH_OFF);
  f16*   Wpl   = (f16*)(ws + WPKL_OFF);
  float* scr   = (float*)(ws + HBUF_OFF);   // fp32 prep scratch, dead before k_caps writes hbuf

  const int GMM = (196 * 196 + NT - 1) / NT;

  k_prep_wd<<<(896 * 800 + NT - 1) / NT, NT, 0, stream>>>(Wd1, Wd1p);
  k_prep_wd<<<(896 * 800 + NT - 1) / NT, NT, 0, stream>>>(Wd2, Wd2p);
  k_prep_wo<<<(784 * 16 + NT - 1) / NT, NT, 0, stream>>>(Wo, WoTws);

  // G = W1^T W2 (slot 0)
  k_mm<<<dim3(GMM, 1), NT, 0, stream>>>(W1, W2, scr, 1, 0, 0, 0, 0);
  // K_1 = W3^T (slot 1); K_{i+1} = K_i @ W3^T (slots 2..8)
  k_tr<<<GMM, NT, 0, stream>>>(W3, scr + (size_t)1 * SSE);
  for (int i = 1; i < 8; ++i)
    k_mm<<<dim3(GMM, 1), NT, 0, stream>>>(scr + (size_t)i * SSE, W3,
                                          scr + (size_t)(i + 1) * SSE, 0, 1, 0, 0, 0);
  // T_i = K_i @ G (i=1..7, batched) ; H_i = T_i @ K_i^T (batched)
  k_mm<<<dim3(GMM, 7), NT, 0, stream>>>(scr + (size_t)1 * SSE, scr,
                                        scr + (size_t)9 * SSE, 0, 0, SSE, 0, SSE);
  k_mm<<<dim3(GMM, 7), NT, 0, stream>>>(scr + (size_t)9 * SSE, scr + (size_t)1 * SSE,
                                        scr + (size_t)16 * SSE, 0, 1, SSE, SSE, SSE);
  // vectors: d-chain, z, g_i, ghat_i, d8
  k_prep_vec<<<1, NT, 0, stream>>>(W2, b1, W3, b3, scr, scr + (size_t)1 * SSE,
                                   scr + (size_t)23 * SSE, d8ws);
  // pack f16 hi/lo weight block
  k_prep_pack<<<(9 * 208 * 224 + NT - 1) / NT, NT, 0, stream>>>(scr, Wph, Wpl);

  k_caps<<<32768 / 16, NTC, 0, stream>>>(x, Wph, Wpl, d8ws, hbuf);
  k_dec<<<dim3(32768 / 128, 7), NT, 0, stream>>>(hbuf, Wd1p, bd1, d1buf, 1);
  k_dec<<<dim3(32768 / 128, 7), NT, 0, stream>>>(d1buf, Wd2p, bd2, hbuf, 0);
  k_logits<<<32768 / 16, NT, 0, stream>>>(hbuf, WoTws, bo, out);
}

// Round 5
// 905.020 us; speedup vs baseline: 1.3713x; 1.3713x over previous
//
#include <hip/hip_runtime.h>
#include <math.h>

#define NT 256
#define NTC 512
typedef _Float16 f16;
typedef _Float16 half8 __attribute__((ext_vector_type(8)));
typedef _Float16 half4 __attribute__((ext_vector_type(4)));
typedef float floatx4 __attribute__((ext_vector_type(4)));

// DPP row_shr sum (VALU-only reduce within 16-lane rows; full sum valid at l15==0 — HW-verified r3)
#define ROWSHR_ADD(v, N) \
  (v) += __int_as_float(__builtin_amdgcn_update_dpp(0, __float_as_int(v), 0x110 | (N), 0xF, 0xF, true))

// ---------------- workspace layout (bytes) ----------------
#define WD1_OFF  0              // 896*800*2 = 1433600
#define WD2_OFF  1433600
#define WOT_OFF  2867200        // 784*16*4 = 50176
#define D8_OFF   2917376        // 196*4 = 784 (pad to 2918400)
#define HBUF_OFF 2918400        // 32768*800*2 = 52428800 -> end 55347200
#define D1_OFF   55347200       // 52428800 -> end 107776000
#define WPKH_OFF 55347200       // 9*208*224*2 = 838656
#define WPKL_OFF 56185856       // 838656 -> end 57024512 (inside d1 region)
#define SSE      38464          // scratch slot stride in floats (>=196*196)
// scratch slots (floats @ hbuf base, dead before k_caps writes hbuf):
// 0:G  1..8:K_1..K_8  9..15:T_1..7  16..22:H_1..7  23:gtab(8*196)  24..30:Kt_1..7

__device__ inline void glds16(const void* g, void* l) {
  __builtin_amdgcn_global_load_lds((const __attribute__((address_space(1))) void*)g,
                                   (__attribute__((address_space(3))) void*)l, 16, 0, 0);
}

// ---------------- prep: decoder weights ----------------
__global__ void k_prep_wd(const float* __restrict__ Wd, f16* __restrict__ W16) {
  int idx = blockIdx.x * NT + threadIdx.x;
  if (idx >= 896 * 800) return;
  int n = idx / 800, k = idx - n * 800;
  W16[idx] = (f16)((n < 784 && k < 784) ? Wd[n * 784 + k] : 0.f);
}

__global__ void k_prep_wo(const float* __restrict__ Wo, float* __restrict__ WoT) {
  int idx = blockIdx.x * NT + threadIdx.x;
  if (idx >= 784 * 16) return;
  int f = idx >> 4, n = idx & 15;
  WoT[idx] = (n < 10) ? Wo[n * 784 + f] : 0.f;
}

// ---------------- prep: split-K 196x196 fp32 GEMM (batched via blockIdx.y) ----------------
// 256 thr = 64 outputs x 4 K-slices(49); wave handles consecutive outputs -> coalesced B (tb=0).
__global__ void k_mm(const float* __restrict__ A0, const float* __restrict__ B0,
                     float* __restrict__ C0, int ta, int tb, int sA, int sB, int sC) {
  const float* A = A0 + (size_t)blockIdx.y * sA;
  const float* B = B0 + (size_t)blockIdx.y * sB;
  float*       C = C0 + (size_t)blockIdx.y * sC;
  __shared__ float red[256];
  const int tid = threadIdx.x;
  const int o = blockIdx.x * 64 + (tid & 63);
  const int ks = tid >> 6;
  float s = 0.f;
  int p = 0, r = 0;
  if (o < 196 * 196) {
    p = o / 196; r = o - p * 196;
    const int c0 = ks * 49;
    #pragma unroll 7
    for (int c = c0; c < c0 + 49; ++c) {
      float a = ta ? A[c * 196 + p] : A[p * 196 + c];
      float b = tb ? B[r * 196 + c] : B[c * 196 + r];
      s += a * b;
    }
  }
  red[tid] = s;
  __syncthreads();
  if (tid < 64 && o < 196 * 196)
    C[p * 196 + r] = red[tid] + red[tid + 64] + red[tid + 128] + red[tid + 192];
}

__global__ void k_tr(const float* __restrict__ A0, float* __restrict__ C0, int sA, int sC) {
  const float* A = A0 + (size_t)blockIdx.y * sA;
  float*       C = C0 + (size_t)blockIdx.y * sC;
  int idx = blockIdx.x * NT + threadIdx.x;
  if (idx >= 196 * 196) return;
  int p = idx / 196, r = idx - p * 196;
  C[p * 196 + r] = A[r * 196 + p];
}

// ---------------- prep: vectors, closed-form (z, c_j, d_i, g_i, ghat_i, d8) ----------------
// d_i = sum_{j<i} c_j with c_j = K_j^T b3 (c_0 = b3); g_i = z + G^T d_i; ghat_i = K_i g_i.
__global__ void k_prep_vec(const float* __restrict__ W2, const float* __restrict__ b1,
                           const float* __restrict__ b3,
                           const float* __restrict__ G, const float* __restrict__ Kbase,
                           float* __restrict__ gtab, float* __restrict__ d8out) {
  __shared__ float z[196], cbuf[8][196], dbuf[8][196], gbuf[8][196], d8s[196];
  const int tid = threadIdx.x;  // 512
  for (int t = tid; t < 196; t += NTC) {
    float s = 0.f;
    for (int f = 0; f < 196; ++f) s += b1[f] * W2[f * 196 + t];
    z[t] = s;
    cbuf[0][t] = b3[t];
  }
  for (int o = tid; o < 7 * 196; o += NTC) {
    int j = o / 196 + 1, t = o - (j - 1) * 196;
    const float* K = Kbase + (size_t)(j - 1) * SSE;
    float s = 0.f;
    for (int n = 0; n < 196; ++n) s += K[n * 196 + t] * b3[n];
    cbuf[j][t] = s;
  }
  __syncthreads();
  for (int o = tid; o < 8 * 196; o += NTC) {
    int i = o / 196, t = o - i * 196;
    float s = 0.f;
    for (int j = 0; j < i; ++j) s += cbuf[j][t];
    dbuf[i][t] = s;
    if (i == 7) d8s[t] = s + cbuf[7][t];
  }
  __syncthreads();
  for (int o = tid; o < 8 * 196; o += NTC) {
    int i = o / 196, t = o - i * 196;
    float s = z[t];
    for (int k = 0; k < 196; ++k) s += G[k * 196 + t] * dbuf[i][k];
    gbuf[i][t] = s;
  }
  __syncthreads();
  for (int o = tid; o < 8 * 196; o += NTC) {
    int i = o / 196, t = o - i * 196;
    float s;
    if (i == 0) {
      s = gbuf[0][t];
    } else {
      const float* K = Kbase + (size_t)(i - 1) * SSE;
      s = 0.f;
      for (int n = 0; n < 196; ++n) s += K[t * 196 + n] * gbuf[i][n];
    }
    gtab[i * 196 + t] = s;
  }
  for (int t = tid; t < 196; t += NTC) d8out[t] = d8s[t];
}

// ---------------- prep: pack Wpk[9 slots][208 n][224 k] f16 hi/lo (unchanged) ----------------
__global__ void k_prep_pack(const float* __restrict__ scr,
                            f16* __restrict__ Wph, f16* __restrict__ Wpl) {
  int idx = blockIdx.x * NT + threadIdx.x;
  if (idx >= 9 * 208 * 224) return;
  int s = idx / (208 * 224), rem = idx - s * (208 * 224);
  int n = rem / 224, k = rem - n * 224;
  float v = 0.f;
  if (k < 196) {
    if (n < 196) {
      const float* M = (s == 0) ? scr
                     : (s < 8 ? (scr + (size_t)(16 + s - 1) * SSE)
                              : (scr + (size_t)8 * SSE));
      v = M[k * 196 + n];
    } else if (n == 196 && s < 8) {
      v = scr[(size_t)23 * SSE + s * 196 + k];
    }
  }
  f16 hi = (f16)v;
  Wph[idx] = hi;
  Wpl[idx] = (f16)(v - (float)hi);
}

// ---------------- capsule kernel (unchanged from r4: 465us, verified) ----------------
__global__ __launch_bounds__(NTC, 4)
void k_caps(const float* __restrict__ x,
            const f16* __restrict__ Wph, const f16* __restrict__ Wpl,
            const float* __restrict__ d8g,
            f16* __restrict__ hbuf) {
  __shared__ __align__(16) char smem[70656];
  f16*   vAhi = (f16*)smem;                 // [64][232]
  f16*   vAlo = (f16*)(smem + 29696);       // [64][232]
  float* Sful = (float*)(smem + 59392);     // [8 i][16 elem][4 t][4 s]
  float* Rl   = (float*)(smem + 67584);     // [8 i][64 row]
  float* Cm   = (float*)(smem + 69632);     // [16 elem][4 t][4 s]

  const int tid  = threadIdx.x;
  const int w    = tid >> 6;
  const int lane = tid & 63;
  const int l15  = lane & 15;
  const int quad = lane >> 4;
  const int e0   = blockIdx.x * 16;
  const bool haveJ1 = (w + 8) < 13;

  for (int idx = tid; idx < 16 * 196; idx += NTC) {
    int elem = idx / 196, g = idx - elem * 196;
    int t = g / 49, f = (g - t * 49) * 4;
    floatx4 v4 = *(const floatx4*)&x[(size_t)(e0 + elem) * 784 + g * 4];
    half4 h4, l4;
    #pragma unroll
    for (int q = 0; q < 4; ++q) {
      f16 h = (f16)v4[q];
      h4[q] = h;
      l4[q] = (f16)(v4[q] - (float)h);
    }
    int vo = (elem * 4 + t) * 232 + f;
    *(half4*)&vAhi[vo] = h4;
    *(half4*)&vAlo[vo] = l4;
  }
  for (int p = tid; p < 64 * 36; p += NTC) {
    int row = p / 36, c = 196 + (p - (p / 36) * 36);
    vAhi[row * 232 + c] = (f16)0;
    vAlo[row * 232 + c] = (f16)0;
  }
  for (int p = tid; p < 2048; p += NTC) Sful[p] = 0.f;
  __syncthreads();

  float vv0[4][4], vv1[4][4];
  {
    int c0 = w * 16 + l15;
    int c1 = 128 + w * 16 + l15;
    #pragma unroll
    for (int mt = 0; mt < 4; ++mt)
      #pragma unroll
      for (int s = 0; s < 4; ++s) {
        int ro = ((mt * 4 + quad) * 4 + s) * 232;
        vv0[mt][s] = (float)vAhi[ro + c0] + (float)vAlo[ro + c0];
        vv1[mt][s] = haveJ1 ? ((float)vAhi[ro + c1] + (float)vAlo[ro + c1]) : 0.f;
      }
  }

  #pragma unroll 1
  for (int i = 0; i < 8; ++i) {
    floatx4 acc0[4], acc1[4];
    #pragma unroll
    for (int mt = 0; mt < 4; ++mt) {
      acc0[mt] = (floatx4){0.f, 0.f, 0.f, 0.f};
      acc1[mt] = (floatx4){0.f, 0.f, 0.f, 0.f};
    }
    const int wb0 = ((i * 208 + w * 16 + l15) * 224) + quad * 8;
    const int wb1 = ((i * 208 + (w + 8) * 16 + l15) * 224) + quad * 8;
    #pragma unroll
    for (int ks = 0; ks < 7; ++ks) {
      half8 ah[4], al[4];
      #pragma unroll
      for (int mt = 0; mt < 4; ++mt) {
        int ao = (mt * 16 + l15) * 232 + ks * 32 + quad * 8;
        ah[mt] = *(const half8*)&vAhi[ao];
        al[mt] = *(const half8*)&vAlo[ao];
      }
      {
        half8 bh = *(const half8*)&Wph[wb0 + ks * 32];
        half8 bl = *(const half8*)&Wpl[wb0 + ks * 32];
        #pragma unroll
        for (int mt = 0; mt < 4; ++mt) {
          acc0[mt] = __builtin_amdgcn_mfma_f32_16x16x32_f16(ah[mt], bh, acc0[mt], 0, 0, 0);
          acc0[mt] = __builtin_amdgcn_mfma_f32_16x16x32_f16(ah[mt], bl, acc0[mt], 0, 0, 0);
          acc0[mt] = __builtin_amdgcn_mfma_f32_16x16x32_f16(al[mt], bh, acc0[mt], 0, 0, 0);
        }
      }
      if (haveJ1) {
        half8 bh = *(const half8*)&Wph[wb1 + ks * 32];
        half8 bl = *(const half8*)&Wpl[wb1 + ks * 32];
        #pragma unroll
        for (int mt = 0; mt < 4; ++mt) {
          acc1[mt] = __builtin_amdgcn_mfma_f32_16x16x32_f16(ah[mt], bh, acc1[mt], 0, 0, 0);
          acc1[mt] = __builtin_amdgcn_mfma_f32_16x16x32_f16(ah[mt], bl, acc1[mt], 0, 0, 0);
          acc1[mt] = __builtin_amdgcn_mfma_f32_16x16x32_f16(al[mt], bh, acc1[mt], 0, 0, 0);
        }
      }
    }
    #pragma unroll
    for (int mt = 0; mt < 4; ++mt) {
      float part[16];
      #pragma unroll
      for (int t = 0; t < 4; ++t)
        #pragma unroll
        for (int s = 0; s < 4; ++s)
          part[t * 4 + s] = acc0[mt][t] * vv0[mt][s] + acc1[mt][t] * vv1[mt][s];
      #pragma unroll
      for (int p = 0; p < 16; ++p) {
        ROWSHR_ADD(part[p], 8);
        ROWSHR_ADD(part[p], 4);
        ROWSHR_ADD(part[p], 2);
        ROWSHR_ADD(part[p], 1);
      }
      if (l15 == 0) {
        int elem = mt * 4 + quad;
        #pragma unroll
        for (int t = 0; t < 4; ++t)
          #pragma unroll
          for (int s = 0; s < 4; ++s)
            atomicAdd(&Sful[((i * 16 + elem) * 4 + t) * 4 + s], part[t * 4 + s]);
      }
    }
    if (w == 4 && l15 == 4) {
      #pragma unroll
      for (int mt = 0; mt < 4; ++mt)
        *(floatx4*)&Rl[i * 64 + mt * 16 + quad * 4] = acc1[mt];
    }
  }
  __syncthreads();

  if (tid < 16) {
    const int e = tid;
    float C[4][4] = {{1,0,0,0},{0,1,0,0},{0,0,1,0},{0,0,0,1}};
    #pragma unroll 1
    for (int i = 0; i < 8; ++i) {
      float M[4][4];
      #pragma unroll
      for (int a = 0; a < 4; ++a) {
        floatx4 mm = *(const floatx4*)&Sful[((i * 16 + e) * 4 + a) * 4];
        #pragma unroll
        for (int b = 0; b < 4; ++b) M[a][b] = mm[b];
      }
      floatx4 rv = *(const floatx4*)&Rl[i * 64 + e * 4];
      float T1[4][4], Cr[4];
      #pragma unroll
      for (int t = 0; t < 4; ++t)
        #pragma unroll
        for (int b = 0; b < 4; ++b)
          T1[t][b] = C[t][0]*M[0][b] + C[t][1]*M[1][b] + C[t][2]*M[2][b] + C[t][3]*M[3][b];
      #pragma unroll
      for (int s = 0; s < 4; ++s)
        Cr[s] = C[s][0]*rv[0] + C[s][1]*rv[1] + C[s][2]*rv[2] + C[s][3]*rv[3];
      float P[4][4];
      #pragma unroll
      for (int t = 0; t < 4; ++t) {
        float S[4];
        #pragma unroll
        for (int s = 0; s < 4; ++s)
          S[s] = T1[t][0]*C[s][0] + T1[t][1]*C[s][1] + T1[t][2]*C[s][2] + T1[t][3]*C[s][3] + Cr[s];
        float m = fmaxf(fmaxf(S[0], S[1]), fmaxf(S[2], S[3]));
        float e0_ = __expf(S[0] - m), e1 = __expf(S[1] - m);
        float e2 = __expf(S[2] - m), e3 = __expf(S[3] - m);
        float inv = 1.f / (e0_ + e1 + e2 + e3);
        P[t][0] = e0_ * inv; P[t][1] = e1 * inv; P[t][2] = e2 * inv; P[t][3] = e3 * inv;
      }
      float Cn[4][4];
      #pragma unroll
      for (int t = 0; t < 4; ++t)
        #pragma unroll
        for (int s = 0; s < 4; ++s)
          Cn[t][s] = P[t][0]*C[0][s] + P[t][1]*C[1][s] + P[t][2]*C[2][s] + P[t][3]*C[3][s];
      #pragma unroll
      for (int t = 0; t < 4; ++t)
        #pragma unroll
        for (int s = 0; s < 4; ++s) C[t][s] = Cn[t][s];
    }
    #pragma unroll
    for (int t = 0; t < 4; ++t)
      *(floatx4*)&Cm[e * 16 + t * 4] = (floatx4){C[t][0], C[t][1], C[t][2], C[t][3]};
  }
  __syncthreads();

  {
    floatx4 acu0[4], acu1[4];
    #pragma unroll
    for (int mt = 0; mt < 4; ++mt) {
      acu0[mt] = (floatx4){0.f, 0.f, 0.f, 0.f};
      acu1[mt] = (floatx4){0.f, 0.f, 0.f, 0.f};
    }
    const int wb0 = ((8 * 208 + w * 16 + l15) * 224) + quad * 8;
    const int wb1 = ((8 * 208 + (w + 8) * 16 + l15) * 224) + quad * 8;
    #pragma unroll
    for (int ks = 0; ks < 7; ++ks) {
      half8 ah[4], al[4];
      #pragma unroll
      for (int mt = 0; mt < 4; ++mt) {
        int ao = (mt * 16 + l15) * 232 + ks * 32 + quad * 8;
        ah[mt] = *(const half8*)&vAhi[ao];
        al[mt] = *(const half8*)&vAlo[ao];
      }
      {
        half8 bh = *(const half8*)&Wph[wb0 + ks * 32];
        half8 bl = *(const half8*)&Wpl[wb0 + ks * 32];
        #pragma unroll
        for (int mt = 0; mt < 4; ++mt) {
          acu0[mt] = __builtin_amdgcn_mfma_f32_16x16x32_f16(ah[mt], bh, acu0[mt], 0, 0, 0);
          acu0[mt] = __builtin_amdgcn_mfma_f32_16x16x32_f16(ah[mt], bl, acu0[mt], 0, 0, 0);
          acu0[mt] = __builtin_amdgcn_mfma_f32_16x16x32_f16(al[mt], bh, acu0[mt], 0, 0, 0);
        }
      }
      if (haveJ1) {
        half8 bh = *(const half8*)&Wph[wb1 + ks * 32];
        half8 bl = *(const half8*)&Wpl[wb1 + ks * 32];
        #pragma unroll
        for (int mt = 0; mt < 4; ++mt) {
          acu1[mt] = __builtin_amdgcn_mfma_f32_16x16x32_f16(ah[mt], bh, acu1[mt], 0, 0, 0);
          acu1[mt] = __builtin_amdgcn_mfma_f32_16x16x32_f16(ah[mt], bl, acu1[mt], 0, 0, 0);
          acu1[mt] = __builtin_amdgcn_mfma_f32_16x16x32_f16(al[mt], bh, acu1[mt], 0, 0, 0);
        }
      }
    }
    const int f0 = w * 16 + l15;
    const int f1 = 128 + w * 16 + l15;
    const bool doF1 = haveJ1 && (f1 < 196);
    float d80 = d8g[f0];
    float d81 = doF1 ? d8g[f1] : 0.f;
    #pragma unroll
    for (int mt = 0; mt < 4; ++mt) {
      int elem = mt * 4 + quad;
      floatx4 c0 = *(const floatx4*)&Cm[elem * 16 + 0];
      floatx4 c1 = *(const floatx4*)&Cm[elem * 16 + 4];
      floatx4 c2 = *(const floatx4*)&Cm[elem * 16 + 8];
      floatx4 c3 = *(const floatx4*)&Cm[elem * 16 + 12];
      {
        floatx4 u = acu0[mt];
        float h0 = c0[0]*u[0] + c0[1]*u[1] + c0[2]*u[2] + c0[3]*u[3] + d80;
        float h1 = c1[0]*u[0] + c1[1]*u[1] + c1[2]*u[2] + c1[3]*u[3] + d80;
        float h2 = c2[0]*u[0] + c2[1]*u[1] + c2[2]*u[2] + c2[3]*u[3] + d80;
        float h3 = c3[0]*u[0] + c3[1]*u[1] + c3[2]*u[2] + c3[3]*u[3] + d80;
        size_t base = (size_t)(e0 + elem) * 800;
        hbuf[base + 0 * 196 + f0] = (f16)h0;
        hbuf[base + 1 * 196 + f0] = (f16)h1;
        hbuf[base + 2 * 196 + f0] = (f16)h2;
        hbuf[base + 3 * 196 + f0] = (f16)h3;
      }
      if (doF1) {
        floatx4 u = acu1[mt];
        float h0 = c0[0]*u[0] + c0[1]*u[1] + c0[2]*u[2] + c0[3]*u[3] + d81;
        float h1 = c1[0]*u[0] + c1[1]*u[1] + c1[2]*u[2] + c1[3]*u[3] + d81;
        float h2 = c2[0]*u[0] + c2[1]*u[1] + c2[2]*u[2] + c2[3]*u[3] + d81;
        float h3 = c3[0]*u[0] + c3[1]*u[1] + c3[2]*u[2] + c3[3]*u[3] + d81;
        size_t base = (size_t)(e0 + elem) * 800;
        hbuf[base + 0 * 196 + f1] = (f16)h0;
        hbuf[base + 1 * 196 + f1] = (f16)h1;
        hbuf[base + 2 * 196 + f1] = (f16)h2;
        hbuf[base + 3 * 196 + f1] = (f16)h3;
      }
    }
  }
  for (int idx = tid; idx < 256; idx += NTC)
    hbuf[(size_t)(e0 + (idx >> 4)) * 800 + 784 + (idx & 15)] = (f16)0;
}

// ---------------- decoder layer GEMM (unchanged) ----------------
__global__ __launch_bounds__(NT, 2)
void k_dec(const f16* __restrict__ A, const f16* __restrict__ Bw,
           const float* __restrict__ bias, f16* __restrict__ C, int do_relu) {
  __shared__ __align__(16) f16 As[128 * 32];
  __shared__ __align__(16) f16 Bs[128 * 32];
  const int tid = threadIdx.x, w = tid >> 6, lane = tid & 63;
  const int l15 = lane & 15, quad = lane >> 4;
  const int m0 = blockIdx.x * 128, n0 = blockIdx.y * 128;
  const int wm = w & 1, wn = w >> 1;
  const int srow = lane >> 2, soff = (lane & 3) * 8;

  floatx4 acc[4][4];
  #pragma unroll
  for (int nt = 0; nt < 4; ++nt) {
    int col = n0 + wn * 64 + nt * 16 + l15;
    float bb = (col < 784) ? bias[col] : 0.f;
    #pragma unroll
    for (int mt = 0; mt < 4; ++mt) acc[mt][nt] = (floatx4){bb, bb, bb, bb};
  }

  for (int kk = 0; kk < 25; ++kk) {
    __syncthreads();
    #pragma unroll
    for (int i = 0; i < 2; ++i) {
      int r = w * 32 + i * 16;
      glds16(&A[(size_t)(m0 + r + srow) * 800 + kk * 32 + soff], &As[r * 32]);
      glds16(&Bw[(size_t)(n0 + r + srow) * 800 + kk * 32 + soff], &Bs[r * 32]);
    }
    __syncthreads();
    half8 af[4], bf[4];
    #pragma unroll
    for (int mt = 0; mt < 4; ++mt)
      af[mt] = *(const half8*)&As[(wm * 64 + mt * 16 + l15) * 32 + quad * 8];
    #pragma unroll
    for (int nt = 0; nt < 4; ++nt)
      bf[nt] = *(const half8*)&Bs[(wn * 64 + nt * 16 + l15) * 32 + quad * 8];
    #pragma unroll
    for (int mt = 0; mt < 4; ++mt)
      #pragma unroll
      for (int nt = 0; nt < 4; ++nt)
        acc[mt][nt] = __builtin_amdgcn_mfma_f32_16x16x32_f16(af[mt], bf[nt], acc[mt][nt], 0, 0, 0);
  }

  #pragma unroll
  for (int nt = 0; nt < 4; ++nt) {
    int gcol = n0 + wn * 64 + nt * 16 + l15;
    if (gcol < 800) {
      #pragma unroll
      for (int mt = 0; mt < 4; ++mt) {
        #pragma unroll
        for (int r = 0; r < 4; ++r) {
          int grow = m0 + wm * 64 + mt * 16 + quad * 4 + r;
          float v = acc[mt][nt][r];
          if (do_relu) v = fmaxf(v, 0.f);
          C[(size_t)grow * 800 + gcol] = (f16)v;
        }
      }
    }
  }
}

// ---------------- logits + softmax (unchanged) ----------------
__global__ __launch_bounds__(NT, 4)
void k_logits(const f16* __restrict__ d2, const float* __restrict__ WoT,
              const float* __restrict__ bo, float* __restrict__ out) {
  __shared__ __align__(16) f16 ds[16 * 800];
  __shared__ float lg[160];
  const int tid = threadIdx.x;
  const size_t e0 = (size_t)blockIdx.x * 16;
  for (int i = tid; i < 16 * 98; i += NT) {
    int e = i / 98, c = (i - e * 98) * 8;
    *(half8*)&ds[e * 800 + c] = *(const half8*)&d2[(e0 + e) * 800 + c];
  }
  __syncthreads();
  {
    int e = tid >> 4, n = tid & 15;
    const f16* dp = &ds[e * 800];
    float s = 0.f;
    #pragma unroll 4
    for (int f = 0; f < 784; ++f) s += (float)dp[f] * WoT[f * 16 + n];
    if (n < 10) lg[e * 10 + n] = s + bo[n];
  }
  __syncthreads();
  if (tid < 16) {
    float l[10], m = -1e30f;
    #pragma unroll
    for (int n = 0; n < 10; ++n) { l[n] = lg[tid * 10 + n]; m = fmaxf(m, l[n]); }
    float sum = 0.f;
    #pragma unroll
    for (int n = 0; n < 10; ++n) { l[n] = __expf(l[n] - m); sum += l[n]; }
    float inv = 1.f / sum;
    #pragma unroll
    for (int n = 0; n < 10; ++n) out[(e0 + tid) * 10 + n] = l[n] * inv;
  }
}

extern "C" void kernel_launch(void* const* d_in, const int* in_sizes, int n_in,
                              void* d_out, int out_size, void* d_ws, size_t ws_size,
                              hipStream_t stream) {
  const float* x   = (const float*)d_in[0];
  const float* W1  = (const float*)d_in[1];
  const float* b1  = (const float*)d_in[2];
  const float* W2  = (const float*)d_in[3];
  // b2 (d_in[4]) cancels in the softmax (row-constant) — unused.
  const float* W3  = (const float*)d_in[5];
  const float* b3  = (const float*)d_in[6];
  const float* Wd1 = (const float*)d_in[7];
  const float* bd1 = (const float*)d_in[8];
  const float* Wd2 = (const float*)d_in[9];
  const float* bd2 = (const float*)d_in[10];
  const float* Wo  = (const float*)d_in[11];
  const float* bo  = (const float*)d_in[12];
  float* out = (float*)d_out;

  char* ws = (char*)d_ws;
  f16*   Wd1p  = (f16*)(ws + WD1_OFF);
  f16*   Wd2p  = (f16*)(ws + WD2_OFF);
  float* WoTws = (float*)(ws + WOT_OFF);
  float* d8ws  = (float*)(ws + D8_OFF);
  f16*   hbuf  = (f16*)(ws + HBUF_OFF);
  f16*   d1buf = (f16*)(ws + D1_OFF);
  f16*   Wph   = (f16*)(ws + WPKH_OFF);
  f16*   Wpl   = (f16*)(ws + WPKL_OFF);
  float* scr   = (float*)(ws + HBUF_OFF);   // fp32 prep scratch, dead before k_caps writes hbuf

  const int GTR = (196 * 196 + NT - 1) / NT;     // 151 blocks (transpose)
  const int GSK = (196 * 196 + 63) / 64;          // 601 blocks (split-K GEMM)

  k_prep_wd<<<(896 * 800 + NT - 1) / NT, NT, 0, stream>>>(Wd1, Wd1p);
  k_prep_wd<<<(896 * 800 + NT - 1) / NT, NT, 0, stream>>>(Wd2, Wd2p);
  k_prep_wo<<<(784 * 16 + NT - 1) / NT, NT, 0, stream>>>(Wo, WoTws);

  // K_1 = W3^T ; G = W1^T W2
  k_tr<<<dim3(GTR, 1), NT, 0, stream>>>(W3, scr + (size_t)1 * SSE, 0, 0);
  k_mm<<<dim3(GSK, 1), NT, 0, stream>>>(W1, W2, scr, 1, 0, 0, 0, 0);
  // K_2 = K_1 @ K_1
  k_mm<<<dim3(GSK, 1), NT, 0, stream>>>(scr + (size_t)1 * SSE, scr + (size_t)1 * SSE,
                                        scr + (size_t)2 * SSE, 0, 0, 0, 0, 0);
  // {K_3,K_4} = K_2 @ {K_1,K_2}
  k_mm<<<dim3(GSK, 2), NT, 0, stream>>>(scr + (size_t)2 * SSE, scr + (size_t)1 * SSE,
                                        scr + (size_t)3 * SSE, 0, 0, 0, SSE, SSE);
  // {K_5..K_8} = K_4 @ {K_1..K_4}
  k_mm<<<dim3(GSK, 4), NT, 0, stream>>>(scr + (size_t)4 * SSE, scr + (size_t)1 * SSE,
                                        scr + (size_t)5 * SSE, 0, 0, 0, SSE, SSE);
  // T_i = K_i @ G (i=1..7) ; Kt_i = K_i^T ; H_i = T_i @ Kt_i
  k_mm<<<dim3(GSK, 7), NT, 0, stream>>>(scr + (size_t)1 * SSE, scr,
                                        scr + (size_t)9 * SSE, 0, 0, SSE, 0, SSE);
  k_tr<<<dim3(GTR, 7), NT, 0, stream>>>(scr + (size_t)1 * SSE, scr + (size_t)24 * SSE, SSE, SSE);
  k_mm<<<dim3(GSK, 7), NT, 0, stream>>>(scr + (size_t)9 * SSE, scr + (size_t)24 * SSE,
                                        scr + (size_t)16 * SSE, 0, 0, SSE, SSE, SSE);
  // vectors (closed-form) + pack
  k_prep_vec<<<1, NTC, 0, stream>>>(W2, b1, b3, scr, scr + (size_t)1 * SSE,
                                    scr + (size_t)23 * SSE, d8ws);
  k_prep_pack<<<(9 * 208 * 224 + NT - 1) / NT, NT, 0, stream>>>(scr, Wph, Wpl);

  k_caps<<<32768 / 16, NTC, 0, stream>>>(x, Wph, Wpl, d8ws, hbuf);
  k_dec<<<dim3(32768 / 128, 7), NT, 0, stream>>>(hbuf, Wd1p, bd1, d1buf, 1);
  k_dec<<<dim3(32768 / 128, 7), NT, 0, stream>>>(d1buf, Wd2p, bd2, hbuf, 0);
  k_logits<<<32768 / 16, NT, 0, stream>>>(hbuf, WoTws, bo, out);
}

// Round 6
// 858.442 us; speedup vs baseline: 1.4457x; 1.0543x over previous
//
#include <hip/hip_runtime.h>
#include <math.h>

#define NT 256
#define NTC 512
typedef _Float16 f16;
typedef _Float16 half8 __attribute__((ext_vector_type(8)));
typedef _Float16 half4 __attribute__((ext_vector_type(4)));
typedef float floatx4 __attribute__((ext_vector_type(4)));

// DPP row_shr sum (VALU-only reduce within 16-lane rows; full sum valid at l15==0 — HW-verified r3)
#define ROWSHR_ADD(v, N) \
  (v) += __int_as_float(__builtin_amdgcn_update_dpp(0, __float_as_int(v), 0x110 | (N), 0xF, 0xF, true))

// ---------------- workspace layout (bytes) ----------------
#define WD1_OFF  0              // 896*800*2 = 1433600
#define WD2_OFF  1433600
#define WOT_OFF  2867200        // 784*16*4 = 50176
#define D8_OFF   2917376        // 196*4 = 784 (pad to 2918400)
#define HBUF_OFF 2918400        // 32768*800*2 = 52428800 -> end 55347200
#define D1_OFF   55347200       // 52428800 -> end 107776000
#define WPKH_OFF 55347200       // 9*208*224*2 = 838656
#define WPKL_OFF 56185856       // 838656 -> end 57024512 (inside d1 region)
#define SSE      38464          // scratch slot stride in floats (>=196*196)
// scratch slots (floats @ hbuf base, dead before k_caps writes hbuf):
// 0:G  1..8:Q_1..Q_8 (Q_i = W3^i; K_i = Q_i^T)  9..15:T_1..7  16..22:H_1..7  23:gtab(8*196)

__device__ inline void glds16(const void* g, void* l) {
  __builtin_amdgcn_global_load_lds((const __attribute__((address_space(1))) void*)g,
                                   (__attribute__((address_space(3))) void*)l, 16, 0, 0);
}

// ---------------- prep: decoder weights ----------------
__global__ void k_prep_wd(const float* __restrict__ Wd, f16* __restrict__ W16) {
  int idx = blockIdx.x * NT + threadIdx.x;
  if (idx >= 896 * 800) return;
  int n = idx / 800, k = idx - n * 800;
  W16[idx] = (f16)((n < 784 && k < 784) ? Wd[n * 784 + k] : 0.f);
}

__global__ void k_prep_wo(const float* __restrict__ Wo, float* __restrict__ WoT) {
  int idx = blockIdx.x * NT + threadIdx.x;
  if (idx >= 784 * 16) return;
  int f = idx >> 4, n = idx & 15;
  WoT[idx] = (n < 10) ? Wo[n * 784 + f] : 0.f;
}

// ---------------- prep: split-K 196x196 fp32 GEMM (batched via blockIdx.y) ----------------
__global__ void k_mm(const float* __restrict__ A0, const float* __restrict__ B0,
                     float* __restrict__ C0, int ta, int tb, int sA, int sB, int sC) {
  const float* A = A0 + (size_t)blockIdx.y * sA;
  const float* B = B0 + (size_t)blockIdx.y * sB;
  float*       C = C0 + (size_t)blockIdx.y * sC;
  __shared__ float red[256];
  const int tid = threadIdx.x;
  const int o = blockIdx.x * 64 + (tid & 63);
  const int ks = tid >> 6;
  float s = 0.f;
  int p = 0, r = 0;
  if (o < 196 * 196) {
    p = o / 196; r = o - p * 196;
    const int c0 = ks * 49;
    #pragma unroll 7
    for (int c = c0; c < c0 + 49; ++c) {
      float a = ta ? A[c * 196 + p] : A[p * 196 + c];
      float b = tb ? B[r * 196 + c] : B[c * 196 + r];
      s += a * b;
    }
  }
  red[tid] = s;
  __syncthreads();
  if (tid < 64 && o < 196 * 196)
    C[p * 196 + r] = red[tid] + red[tid + 64] + red[tid + 128] + red[tid + 192];
}

// ---------------- prep: G = W1^T W2 (blocks 0..600) + copy W3 -> Q1 slot (blocks 601..) ----
__global__ void k_prep_gq(const float* __restrict__ W1, const float* __restrict__ W2,
                          const float* __restrict__ W3, float* __restrict__ scr) {
  if (blockIdx.x < 601) {
    __shared__ float red[256];
    const int tid = threadIdx.x;
    const int o = blockIdx.x * 64 + (tid & 63);
    const int ks = tid >> 6;
    float s = 0.f;
    int p = 0, r = 0;
    if (o < 196 * 196) {
      p = o / 196; r = o - p * 196;
      const int c0 = ks * 49;
      #pragma unroll 7
      for (int c = c0; c < c0 + 49; ++c)
        s += W1[c * 196 + p] * W2[c * 196 + r];
    }
    red[tid] = s;
    __syncthreads();
    if (tid < 64 && o < 196 * 196)
      scr[p * 196 + r] = red[tid] + red[tid + 64] + red[tid + 128] + red[tid + 192];
  } else {
    int idx = (blockIdx.x - 601) * NT + threadIdx.x;
    if (idx < 196 * 196) scr[(size_t)SSE + idx] = W3[idx];
  }
}

// ---------------- prep: vectors, one block per i ----------------
// c_0 = b3, c_{j+1} = W3 c_j ; d_i = sum_{j<i} c_j ; g_i = z + G^T d_i ;
// ghat_i = K_i g_i = Q_i^T g_i ; d8 = d_7 + c_7 (block 7).
__global__ void k_prep_vec(const float* __restrict__ W2, const float* __restrict__ b1,
                           const float* __restrict__ b3,
                           const float* __restrict__ G, const float* __restrict__ Qbase,
                           float* __restrict__ gtab, float* __restrict__ d8out) {
  __shared__ float z[196], cj[196], d[196], tmp[196];
  const int i = blockIdx.x;      // 0..7
  const int tid = threadIdx.x;   // 256
  const float* W3 = Qbase;       // Q1 slot = W3 copy
  for (int t = tid; t < 196; t += NT) {
    float s = 0.f;
    for (int f = 0; f < 196; ++f) s += b1[f] * W2[f * 196 + t];
    z[t] = s;
    d[t] = 0.f;
    cj[t] = b3[t];
  }
  __syncthreads();
  for (int j = 0; j < i; ++j) {
    for (int t = tid; t < 196; t += NT) {
      float s = 0.f;
      for (int c = 0; c < 196; ++c) s += W3[t * 196 + c] * cj[c];
      tmp[t] = s;
      d[t] += cj[t];
    }
    __syncthreads();
    for (int t = tid; t < 196; t += NT) cj[t] = tmp[t];
    __syncthreads();
  }
  if (i == 7) {
    for (int t = tid; t < 196; t += NT) d8out[t] = d[t] + cj[t];
  }
  // g = z + G^T d  (into tmp)
  for (int t = tid; t < 196; t += NT) {
    float s = z[t];
    for (int k = 0; k < 196; ++k) s += G[k * 196 + t] * d[k];
    tmp[t] = s;
  }
  __syncthreads();
  for (int t = tid; t < 196; t += NT) {
    float s;
    if (i == 0) {
      s = tmp[t];
    } else {
      const float* Qi = Qbase + (size_t)(i - 1) * SSE;
      s = 0.f;
      for (int n = 0; n < 196; ++n) s += Qi[n * 196 + t] * tmp[n];
    }
    gtab[i * 196 + t] = s;
  }
}

// ---------------- prep: pack Wpk[9 slots][208 n][224 k] f16 hi/lo ----------------
// slot s<8: B[k][n] = H_s[k][n] (H_0 = G); col n==196 carries ghat_s[k].
// slot 8: B[k][n] = K_8[k][n] = Q_8[n][k] (transposed read).
__global__ void k_prep_pack(const float* __restrict__ scr,
                            f16* __restrict__ Wph, f16* __restrict__ Wpl) {
  int idx = blockIdx.x * NT + threadIdx.x;
  if (idx >= 9 * 208 * 224) return;
  int s = idx / (208 * 224), rem = idx - s * (208 * 224);
  int n = rem / 224, k = rem - n * 224;
  float v = 0.f;
  if (k < 196) {
    if (n < 196) {
      if (s == 8) {
        v = scr[(size_t)8 * SSE + n * 196 + k];          // K8 = Q8^T
      } else {
        const float* M = (s == 0) ? scr : (scr + (size_t)(16 + s - 1) * SSE);
        v = M[k * 196 + n];
      }
    } else if (n == 196 && s < 8) {
      v = scr[(size_t)23 * SSE + s * 196 + k];
    }
  }
  f16 hi = (f16)v;
  Wph[idx] = hi;
  Wpl[idx] = (f16)(v - (float)hi);
}

// ---------------- capsule kernel: 8 Y_i GEMMs + 4x4 C-chain + V_8 ----------------
// r6 deltas vs r5 (verified 455us): Sful stride 16->20 floats (atomic bank spread),
// i-loop unroll 2 (GEMM(i+1) loads/MFMA overlap reduce(i) VALU).
__global__ __launch_bounds__(NTC, 4)
void k_caps(const float* __restrict__ x,
            const f16* __restrict__ Wph, const f16* __restrict__ Wpl,
            const float* __restrict__ d8g,
            f16* __restrict__ hbuf) {
  __shared__ __align__(16) char smem[72704];
  f16*   vAhi = (f16*)smem;                 // [64][232]
  f16*   vAlo = (f16*)(smem + 29696);       // [64][232]
  float* Sful = (float*)(smem + 59392);     // [8 i][16 elem][20] (t*4+s in first 16)
  float* Rl   = (float*)(smem + 69632);     // [8 i][64 row]
  float* Cm   = (float*)(smem + 71680);     // [16 elem][4 t][4 s]

  const int tid  = threadIdx.x;
  const int w    = tid >> 6;
  const int lane = tid & 63;
  const int l15  = lane & 15;
  const int quad = lane >> 4;
  const int e0   = blockIdx.x * 16;
  const bool haveJ1 = (w + 8) < 13;

  for (int idx = tid; idx < 16 * 196; idx += NTC) {
    int elem = idx / 196, g = idx - elem * 196;
    int t = g / 49, f = (g - t * 49) * 4;
    floatx4 v4 = *(const floatx4*)&x[(size_t)(e0 + elem) * 784 + g * 4];
    half4 h4, l4;
    #pragma unroll
    for (int q = 0; q < 4; ++q) {
      f16 h = (f16)v4[q];
      h4[q] = h;
      l4[q] = (f16)(v4[q] - (float)h);
    }
    int vo = (elem * 4 + t) * 232 + f;
    *(half4*)&vAhi[vo] = h4;
    *(half4*)&vAlo[vo] = l4;
  }
  for (int p = tid; p < 64 * 36; p += NTC) {
    int row = p / 36, c = 196 + (p - (p / 36) * 36);
    vAhi[row * 232 + c] = (f16)0;
    vAlo[row * 232 + c] = (f16)0;
  }
  for (int p = tid; p < 8 * 16 * 20; p += NTC) Sful[p] = 0.f;
  __syncthreads();

  float vv0[4][4], vv1[4][4];
  {
    int c0 = w * 16 + l15;
    int c1 = 128 + w * 16 + l15;
    #pragma unroll
    for (int mt = 0; mt < 4; ++mt)
      #pragma unroll
      for (int s = 0; s < 4; ++s) {
        int ro = ((mt * 4 + quad) * 4 + s) * 232;
        vv0[mt][s] = (float)vAhi[ro + c0] + (float)vAlo[ro + c0];
        vv1[mt][s] = haveJ1 ? ((float)vAhi[ro + c1] + (float)vAlo[ro + c1]) : 0.f;
      }
  }

  #pragma unroll 2
  for (int i = 0; i < 8; ++i) {
    floatx4 acc0[4], acc1[4];
    #pragma unroll
    for (int mt = 0; mt < 4; ++mt) {
      acc0[mt] = (floatx4){0.f, 0.f, 0.f, 0.f};
      acc1[mt] = (floatx4){0.f, 0.f, 0.f, 0.f};
    }
    const int wb0 = ((i * 208 + w * 16 + l15) * 224) + quad * 8;
    const int wb1 = ((i * 208 + (w + 8) * 16 + l15) * 224) + quad * 8;
    #pragma unroll
    for (int ks = 0; ks < 7; ++ks) {
      half8 ah[4], al[4];
      #pragma unroll
      for (int mt = 0; mt < 4; ++mt) {
        int ao = (mt * 16 + l15) * 232 + ks * 32 + quad * 8;
        ah[mt] = *(const half8*)&vAhi[ao];
        al[mt] = *(const half8*)&vAlo[ao];
      }
      {
        half8 bh = *(const half8*)&Wph[wb0 + ks * 32];
        half8 bl = *(const half8*)&Wpl[wb0 + ks * 32];
        #pragma unroll
        for (int mt = 0; mt < 4; ++mt) {
          acc0[mt] = __builtin_amdgcn_mfma_f32_16x16x32_f16(ah[mt], bh, acc0[mt], 0, 0, 0);
          acc0[mt] = __builtin_amdgcn_mfma_f32_16x16x32_f16(ah[mt], bl, acc0[mt], 0, 0, 0);
          acc0[mt] = __builtin_amdgcn_mfma_f32_16x16x32_f16(al[mt], bh, acc0[mt], 0, 0, 0);
        }
      }
      if (haveJ1) {
        half8 bh = *(const half8*)&Wph[wb1 + ks * 32];
        half8 bl = *(const half8*)&Wpl[wb1 + ks * 32];
        #pragma unroll
        for (int mt = 0; mt < 4; ++mt) {
          acc1[mt] = __builtin_amdgcn_mfma_f32_16x16x32_f16(ah[mt], bh, acc1[mt], 0, 0, 0);
          acc1[mt] = __builtin_amdgcn_mfma_f32_16x16x32_f16(ah[mt], bl, acc1[mt], 0, 0, 0);
          acc1[mt] = __builtin_amdgcn_mfma_f32_16x16x32_f16(al[mt], bh, acc1[mt], 0, 0, 0);
        }
      }
    }
    #pragma unroll
    for (int mt = 0; mt < 4; ++mt) {
      float part[16];
      #pragma unroll
      for (int t = 0; t < 4; ++t)
        #pragma unroll
        for (int s = 0; s < 4; ++s)
          part[t * 4 + s] = acc0[mt][t] * vv0[mt][s] + acc1[mt][t] * vv1[mt][s];
      #pragma unroll
      for (int p = 0; p < 16; ++p) {
        ROWSHR_ADD(part[p], 8);
        ROWSHR_ADD(part[p], 4);
        ROWSHR_ADD(part[p], 2);
        ROWSHR_ADD(part[p], 1);
      }
      if (l15 == 0) {
        int elem = mt * 4 + quad;
        #pragma unroll
        for (int t = 0; t < 4; ++t)
          #pragma unroll
          for (int s = 0; s < 4; ++s)
            atomicAdd(&Sful[(i * 16 + elem) * 20 + t * 4 + s], part[t * 4 + s]);
      }
    }
    if (w == 4 && l15 == 4) {
      #pragma unroll
      for (int mt = 0; mt < 4; ++mt)
        *(floatx4*)&Rl[i * 64 + mt * 16 + quad * 4] = acc1[mt];
    }
  }
  __syncthreads();

  if (tid < 16) {
    const int e = tid;
    float C[4][4] = {{1,0,0,0},{0,1,0,0},{0,0,1,0},{0,0,0,1}};
    #pragma unroll 1
    for (int i = 0; i < 8; ++i) {
      float M[4][4];
      #pragma unroll
      for (int a = 0; a < 4; ++a) {
        floatx4 mm = *(const floatx4*)&Sful[(i * 16 + e) * 20 + a * 4];
        #pragma unroll
        for (int b = 0; b < 4; ++b) M[a][b] = mm[b];
      }
      floatx4 rv = *(const floatx4*)&Rl[i * 64 + e * 4];
      float T1[4][4], Cr[4];
      #pragma unroll
      for (int t = 0; t < 4; ++t)
        #pragma unroll
        for (int b = 0; b < 4; ++b)
          T1[t][b] = C[t][0]*M[0][b] + C[t][1]*M[1][b] + C[t][2]*M[2][b] + C[t][3]*M[3][b];
      #pragma unroll
      for (int s = 0; s < 4; ++s)
        Cr[s] = C[s][0]*rv[0] + C[s][1]*rv[1] + C[s][2]*rv[2] + C[s][3]*rv[3];
      float P[4][4];
      #pragma unroll
      for (int t = 0; t < 4; ++t) {
        float S[4];
        #pragma unroll
        for (int s = 0; s < 4; ++s)
          S[s] = T1[t][0]*C[s][0] + T1[t][1]*C[s][1] + T1[t][2]*C[s][2] + T1[t][3]*C[s][3] + Cr[s];
        float m = fmaxf(fmaxf(S[0], S[1]), fmaxf(S[2], S[3]));
        float e0_ = __expf(S[0] - m), e1 = __expf(S[1] - m);
        float e2 = __expf(S[2] - m), e3 = __expf(S[3] - m);
        float inv = 1.f / (e0_ + e1 + e2 + e3);
        P[t][0] = e0_ * inv; P[t][1] = e1 * inv; P[t][2] = e2 * inv; P[t][3] = e3 * inv;
      }
      float Cn[4][4];
      #pragma unroll
      for (int t = 0; t < 4; ++t)
        #pragma unroll
        for (int s = 0; s < 4; ++s)
          Cn[t][s] = P[t][0]*C[0][s] + P[t][1]*C[1][s] + P[t][2]*C[2][s] + P[t][3]*C[3][s];
      #pragma unroll
      for (int t = 0; t < 4; ++t)
        #pragma unroll
        for (int s = 0; s < 4; ++s) C[t][s] = Cn[t][s];
    }
    #pragma unroll
    for (int t = 0; t < 4; ++t)
      *(floatx4*)&Cm[e * 16 + t * 4] = (floatx4){C[t][0], C[t][1], C[t][2], C[t][3]};
  }
  __syncthreads();

  {
    floatx4 acu0[4], acu1[4];
    #pragma unroll
    for (int mt = 0; mt < 4; ++mt) {
      acu0[mt] = (floatx4){0.f, 0.f, 0.f, 0.f};
      acu1[mt] = (floatx4){0.f, 0.f, 0.f, 0.f};
    }
    const int wb0 = ((8 * 208 + w * 16 + l15) * 224) + quad * 8;
    const int wb1 = ((8 * 208 + (w + 8) * 16 + l15) * 224) + quad * 8;
    #pragma unroll
    for (int ks = 0; ks < 7; ++ks) {
      half8 ah[4], al[4];
      #pragma unroll
      for (int mt = 0; mt < 4; ++mt) {
        int ao = (mt * 16 + l15) * 232 + ks * 32 + quad * 8;
        ah[mt] = *(const half8*)&vAhi[ao];
        al[mt] = *(const half8*)&vAlo[ao];
      }
      {
        half8 bh = *(const half8*)&Wph[wb0 + ks * 32];
        half8 bl = *(const half8*)&Wpl[wb0 + ks * 32];
        #pragma unroll
        for (int mt = 0; mt < 4; ++mt) {
          acu0[mt] = __builtin_amdgcn_mfma_f32_16x16x32_f16(ah[mt], bh, acu0[mt], 0, 0, 0);
          acu0[mt] = __builtin_amdgcn_mfma_f32_16x16x32_f16(ah[mt], bl, acu0[mt], 0, 0, 0);
          acu0[mt] = __builtin_amdgcn_mfma_f32_16x16x32_f16(al[mt], bh, acu0[mt], 0, 0, 0);
        }
      }
      if (haveJ1) {
        half8 bh = *(const half8*)&Wph[wb1 + ks * 32];
        half8 bl = *(const half8*)&Wpl[wb1 + ks * 32];
        #pragma unroll
        for (int mt = 0; mt < 4; ++mt) {
          acu1[mt] = __builtin_amdgcn_mfma_f32_16x16x32_f16(ah[mt], bh, acu1[mt], 0, 0, 0);
          acu1[mt] = __builtin_amdgcn_mfma_f32_16x16x32_f16(ah[mt], bl, acu1[mt], 0, 0, 0);
          acu1[mt] = __builtin_amdgcn_mfma_f32_16x16x32_f16(al[mt], bh, acu1[mt], 0, 0, 0);
        }
      }
    }
    const int f0 = w * 16 + l15;
    const int f1 = 128 + w * 16 + l15;
    const bool doF1 = haveJ1 && (f1 < 196);
    float d80 = d8g[f0];
    float d81 = doF1 ? d8g[f1] : 0.f;
    #pragma unroll
    for (int mt = 0; mt < 4; ++mt) {
      int elem = mt * 4 + quad;
      floatx4 c0 = *(const floatx4*)&Cm[elem * 16 + 0];
      floatx4 c1 = *(const floatx4*)&Cm[elem * 16 + 4];
      floatx4 c2 = *(const floatx4*)&Cm[elem * 16 + 8];
      floatx4 c3 = *(const floatx4*)&Cm[elem * 16 + 12];
      {
        floatx4 u = acu0[mt];
        float h0 = c0[0]*u[0] + c0[1]*u[1] + c0[2]*u[2] + c0[3]*u[3] + d80;
        float h1 = c1[0]*u[0] + c1[1]*u[1] + c1[2]*u[2] + c1[3]*u[3] + d80;
        float h2 = c2[0]*u[0] + c2[1]*u[1] + c2[2]*u[2] + c2[3]*u[3] + d80;
        float h3 = c3[0]*u[0] + c3[1]*u[1] + c3[2]*u[2] + c3[3]*u[3] + d80;
        size_t base = (size_t)(e0 + elem) * 800;
        hbuf[base + 0 * 196 + f0] = (f16)h0;
        hbuf[base + 1 * 196 + f0] = (f16)h1;
        hbuf[base + 2 * 196 + f0] = (f16)h2;
        hbuf[base + 3 * 196 + f0] = (f16)h3;
      }
      if (doF1) {
        floatx4 u = acu1[mt];
        float h0 = c0[0]*u[0] + c0[1]*u[1] + c0[2]*u[2] + c0[3]*u[3] + d81;
        float h1 = c1[0]*u[0] + c1[1]*u[1] + c1[2]*u[2] + c1[3]*u[3] + d81;
        float h2 = c2[0]*u[0] + c2[1]*u[1] + c2[2]*u[2] + c2[3]*u[3] + d81;
        float h3 = c3[0]*u[0] + c3[1]*u[1] + c3[2]*u[2] + c3[3]*u[3] + d81;
        size_t base = (size_t)(e0 + elem) * 800;
        hbuf[base + 0 * 196 + f1] = (f16)h0;
        hbuf[base + 1 * 196 + f1] = (f16)h1;
        hbuf[base + 2 * 196 + f1] = (f16)h2;
        hbuf[base + 3 * 196 + f1] = (f16)h3;
      }
    }
  }
  for (int idx = tid; idx < 256; idx += NTC)
    hbuf[(size_t)(e0 + (idx >> 4)) * 800 + 784 + (idx & 15)] = (f16)0;
}

// ---------------- decoder layer GEMM (unchanged) ----------------
__global__ __launch_bounds__(NT, 2)
void k_dec(const f16* __restrict__ A, const f16* __restrict__ Bw,
           const float* __restrict__ bias, f16* __restrict__ C, int do_relu) {
  __shared__ __align__(16) f16 As[128 * 32];
  __shared__ __align__(16) f16 Bs[128 * 32];
  const int tid = threadIdx.x, w = tid >> 6, lane = tid & 63;
  const int l15 = lane & 15, quad = lane >> 4;
  const int m0 = blockIdx.x * 128, n0 = blockIdx.y * 128;
  const int wm = w & 1, wn = w >> 1;
  const int srow = lane >> 2, soff = (lane & 3) * 8;

  floatx4 acc[4][4];
  #pragma unroll
  for (int nt = 0; nt < 4; ++nt) {
    int col = n0 + wn * 64 + nt * 16 + l15;
    float bb = (col < 784) ? bias[col] : 0.f;
    #pragma unroll
    for (int mt = 0; mt < 4; ++mt) acc[mt][nt] = (floatx4){bb, bb, bb, bb};
  }

  for (int kk = 0; kk < 25; ++kk) {
    __syncthreads();
    #pragma unroll
    for (int i = 0; i < 2; ++i) {
      int r = w * 32 + i * 16;
      glds16(&A[(size_t)(m0 + r + srow) * 800 + kk * 32 + soff], &As[r * 32]);
      glds16(&Bw[(size_t)(n0 + r + srow) * 800 + kk * 32 + soff], &Bs[r * 32]);
    }
    __syncthreads();
    half8 af[4], bf[4];
    #pragma unroll
    for (int mt = 0; mt < 4; ++mt)
      af[mt] = *(const half8*)&As[(wm * 64 + mt * 16 + l15) * 32 + quad * 8];
    #pragma unroll
    for (int nt = 0; nt < 4; ++nt)
      bf[nt] = *(const half8*)&Bs[(wn * 64 + nt * 16 + l15) * 32 + quad * 8];
    #pragma unroll
    for (int mt = 0; mt < 4; ++mt)
      #pragma unroll
      for (int nt = 0; nt < 4; ++nt)
        acc[mt][nt] = __builtin_amdgcn_mfma_f32_16x16x32_f16(af[mt], bf[nt], acc[mt][nt], 0, 0, 0);
  }

  #pragma unroll
  for (int nt = 0; nt < 4; ++nt) {
    int gcol = n0 + wn * 64 + nt * 16 + l15;
    if (gcol < 800) {
      #pragma unroll
      for (int mt = 0; mt < 4; ++mt) {
        #pragma unroll
        for (int r = 0; r < 4; ++r) {
          int grow = m0 + wm * 64 + mt * 16 + quad * 4 + r;
          float v = acc[mt][nt][r];
          if (do_relu) v = fmaxf(v, 0.f);
          C[(size_t)grow * 800 + gcol] = (f16)v;
        }
      }
    }
  }
}

// ---------------- logits + softmax (unchanged) ----------------
__global__ __launch_bounds__(NT, 4)
void k_logits(const f16* __restrict__ d2, const float* __restrict__ WoT,
              const float* __restrict__ bo, float* __restrict__ out) {
  __shared__ __align__(16) f16 ds[16 * 800];
  __shared__ float lg[160];
  const int tid = threadIdx.x;
  const size_t e0 = (size_t)blockIdx.x * 16;
  for (int i = tid; i < 16 * 98; i += NT) {
    int e = i / 98, c = (i - e * 98) * 8;
    *(half8*)&ds[e * 800 + c] = *(const half8*)&d2[(e0 + e) * 800 + c];
  }
  __syncthreads();
  {
    int e = tid >> 4, n = tid & 15;
    const f16* dp = &ds[e * 800];
    float s = 0.f;
    #pragma unroll 4
    for (int f = 0; f < 784; ++f) s += (float)dp[f] * WoT[f * 16 + n];
    if (n < 10) lg[e * 10 + n] = s + bo[n];
  }
  __syncthreads();
  if (tid < 16) {
    float l[10], m = -1e30f;
    #pragma unroll
    for (int n = 0; n < 10; ++n) { l[n] = lg[tid * 10 + n]; m = fmaxf(m, l[n]); }
    float sum = 0.f;
    #pragma unroll
    for (int n = 0; n < 10; ++n) { l[n] = __expf(l[n] - m); sum += l[n]; }
    float inv = 1.f / sum;
    #pragma unroll
    for (int n = 0; n < 10; ++n) out[(e0 + tid) * 10 + n] = l[n] * inv;
  }
}

extern "C" void kernel_launch(void* const* d_in, const int* in_sizes, int n_in,
                              void* d_out, int out_size, void* d_ws, size_t ws_size,
                              hipStream_t stream) {
  const float* x   = (const float*)d_in[0];
  const float* W1  = (const float*)d_in[1];
  const float* b1  = (const float*)d_in[2];
  const float* W2  = (const float*)d_in[3];
  // b2 (d_in[4]) cancels in the softmax (row-constant) — unused.
  const float* W3  = (const float*)d_in[5];
  const float* b3  = (const float*)d_in[6];
  const float* Wd1 = (const float*)d_in[7];
  const float* bd1 = (const float*)d_in[8];
  const float* Wd2 = (const float*)d_in[9];
  const float* bd2 = (const float*)d_in[10];
  const float* Wo  = (const float*)d_in[11];
  const float* bo  = (const float*)d_in[12];
  float* out = (float*)d_out;

  char* ws = (char*)d_ws;
  f16*   Wd1p  = (f16*)(ws + WD1_OFF);
  f16*   Wd2p  = (f16*)(ws + WD2_OFF);
  float* WoTws = (float*)(ws + WOT_OFF);
  float* d8ws  = (float*)(ws + D8_OFF);
  f16*   hbuf  = (f16*)(ws + HBUF_OFF);
  f16*   d1buf = (f16*)(ws + D1_OFF);
  f16*   Wph   = (f16*)(ws + WPKH_OFF);
  f16*   Wpl   = (f16*)(ws + WPKL_OFF);
  float* scr   = (float*)(ws + HBUF_OFF);   // fp32 prep scratch, dead before k_caps writes hbuf

  const int GSK = (196 * 196 + 63) / 64;          // 601 blocks (split-K GEMM)
  const int GCP = (196 * 196 + NT - 1) / NT;      // 151 blocks (copy part)

  k_prep_wd<<<(896 * 800 + NT - 1) / NT, NT, 0, stream>>>(Wd1, Wd1p);
  k_prep_wd<<<(896 * 800 + NT - 1) / NT, NT, 0, stream>>>(Wd2, Wd2p);
  k_prep_wo<<<(784 * 16 + NT - 1) / NT, NT, 0, stream>>>(Wo, WoTws);

  // G = W1^T W2 (slot 0) + copy W3 -> Q1 (slot 1), one launch
  k_prep_gq<<<GSK + GCP, NT, 0, stream>>>(W1, W2, W3, scr);
  // Q2 = W3 @ W3
  k_mm<<<dim3(GSK, 1), NT, 0, stream>>>(W3, W3, scr + (size_t)2 * SSE, 0, 0, 0, 0, 0);
  // {Q3,Q4} = Q2 @ {Q1,Q2}
  k_mm<<<dim3(GSK, 2), NT, 0, stream>>>(scr + (size_t)2 * SSE, scr + (size_t)1 * SSE,
                                        scr + (size_t)3 * SSE, 0, 0, 0, SSE, SSE);
  // {Q5..Q8} = Q4 @ {Q1..Q4}
  k_mm<<<dim3(GSK, 4), NT, 0, stream>>>(scr + (size_t)4 * SSE, scr + (size_t)1 * SSE,
                                        scr + (size_t)5 * SSE, 0, 0, 0, SSE, SSE);
  // T_i = K_i G = Q_i^T G (i=1..7, ta=1 coalesced)
  k_mm<<<dim3(GSK, 7), NT, 0, stream>>>(scr + (size_t)1 * SSE, scr,
                                        scr + (size_t)9 * SSE, 1, 0, SSE, 0, SSE);
  // H_i = T_i K_i^T = T_i Q_i
  k_mm<<<dim3(GSK, 7), NT, 0, stream>>>(scr + (size_t)9 * SSE, scr + (size_t)1 * SSE,
                                        scr + (size_t)16 * SSE, 0, 0, SSE, SSE, SSE);
  // vectors: one block per i
  k_prep_vec<<<8, NT, 0, stream>>>(W2, b1, b3, scr, scr + (size_t)1 * SSE,
                                   scr + (size_t)23 * SSE, d8ws);
  // pack f16 hi/lo weight block
  k_prep_pack<<<(9 * 208 * 224 + NT - 1) / NT, NT, 0, stream>>>(scr, Wph, Wpl);

  k_caps<<<32768 / 16, NTC, 0, stream>>>(x, Wph, Wpl, d8ws, hbuf);
  k_dec<<<dim3(32768 / 128, 7), NT, 0, stream>>>(hbuf, Wd1p, bd1, d1buf, 1);
  k_dec<<<dim3(32768 / 128, 7), NT, 0, stream>>>(d1buf, Wd2p, bd2, hbuf, 0);
  k_logits<<<32768 / 16, NT, 0, stream>>>(hbuf, WoTws, bo, out);
}